// Round 11
// baseline (6282.601 us; speedup 1.0000x reference)
//
#include <hip/hip_runtime.h>
#include <math.h>

#define BDIM 256
typedef __bf16 bf16;
typedef __bf16 bf16x4 __attribute__((ext_vector_type(4)));
typedef __bf16 bf16x8 __attribute__((ext_vector_type(8)));
typedef float f32x4 __attribute__((ext_vector_type(4)));

constexpr int B_ = 4, H_ = 768, W_ = 768;
constexpr int HW_ = H_ * W_;                 // 589824
constexpr int TS = 16;                       // spatial tile 16x16 px/block
constexpr int NTB = W_ / TS;                 // 48
constexpr int NBLK = HW_ / (TS * TS);        // 2304 blocks per sample

// per-layer stats scratch strides (max nb = 4 samples, 48 floats each)
constexpr int LSTRIDE = 4 * 48;              // floats per layer (acc / stats)

// ---------------------------------------------------------------------------
// Weight repack: [COUT][CIN][3][3] fp32 -> padded bf16 [NT*16][KPP],
// k = tap*CINP + ci, zero everywhere outside (n<COUT, tap<9, ci<CIN).
// ---------------------------------------------------------------------------
__device__ void repack_one(const float* __restrict__ src, bf16* __restrict__ dst,
                           int CIN, int CINP, int COUT, int NT16, int KPP)
{
    const int n_ = NT16 * KPP;
    for (int idx = threadIdx.x; idx < n_; idx += BDIM) {
        const int n = idx / KPP, k = idx - n * KPP;
        const int tap = k / CINP, ci = k - tap * CINP;
        float v = 0.f;
        if (n < COUT && tap < 9 && ci < CIN)
            v = src[(n * CIN + ci) * 9 + tap];
        dst[idx] = (bf16)v;
    }
}

__global__ __launch_bounds__(BDIM) void repack_all(
    const float* w0, const float* w1, const float* w2, const float* w3,
    const float* w4, const float* w5, const float* wf,
    bf16* r0, bf16* r1, bf16* r2, bf16* r3, bf16* r4, bf16* r5, bf16* rf)
{
    switch (blockIdx.x) {
        case 0: repack_one(w0, r0, 1,  8,  4,  16, 104); break;
        case 1: repack_one(w1, r1, 4,  8,  8,  16, 104); break;
        case 2: repack_one(w2, r2, 8,  8,  12, 16, 104); break;
        case 3: repack_one(w3, r3, 12, 16, 16, 16, 168); break;
        case 4: repack_one(w4, r4, 16, 16, 20, 32, 168); break;
        case 5: repack_one(w5, r5, 20, 24, 24, 32, 232); break;
        case 6: repack_one(wf, rf, 24, 24, 6,  16, 232); break;
    }
}

// zero the per-layer stat accumulators + counters (once per iteration)
__global__ __launch_bounds__(BDIM) void zero_stats(
    float* __restrict__ acc, unsigned* __restrict__ cnt)
{
    for (int i = threadIdx.x; i < 6 * LSTRIDE; i += BDIM) acc[i] = 0.f;
    if (threadIdx.x < 24) cnt[threadIdx.x] = 0u;
}

// ---------------------------------------------------------------------------
// bf16-MFMA conv 3x3 (dilated, SAME) + bias, NHWC, nb samples (grid=nb*NBLK).
// Halo tile staged channel-innermost bf16 (prev-layer norm+relu fused, OOB=0).
// GEMM: M=256 px, N=COUT (NT x16), K=9*CINP (KS x32). fp32 accum.
// Weights from global/L1; K-loop software-pipelined one ks ahead.
// InstanceNorm stats: per-block sums atomically accumulated into accL; the
// LAST block per sample (counter) computes mean/invstd into statsL — this
// replaces the separate reduce_stats launches.
// Epilogue round-trips through LDS for contiguous per-pixel global stores.
// ---------------------------------------------------------------------------
template <int CIN, int CINP, int COUT, int DIL, bool FIRST>
__global__ __launch_bounds__(BDIM) void conv_mfma(
    const void* __restrict__ inv,        // FIRST: fp32 x; else bf16 y_prev
    const float* __restrict__ prevStats, // [nb][CIN][2] (mean, invstd)
    const bf16* __restrict__ wp,         // packed [NT*16][KPP]
    const float* __restrict__ bias,      // [COUT] fp32
    bf16* __restrict__ y,                // [nb][H][W][COUT]
    float* __restrict__ accL,            // [nb][48] atomic accumulators
    unsigned* __restrict__ cntL,         // [nb] block counters
    float* __restrict__ statsL)          // [nb][COUT][2] out (mean, invstd)
{
    constexpr int TW = TS + 2 * DIL;
    constexpr int KP = ((9 * CINP + 31) / 32) * 32;
    constexpr int KPP = KP + 8;
    constexpr int NT = (COUT + 15) / 16;
    constexpr int KS = KP / 32;
    constexpr int CSTR = (CINP == 16) ? 24 : CINP;   // multiple of 8 (b128 align)
    __shared__ __align__(16) bf16 tile[TW * TW * CSTR];
    __shared__ float sred[4][2 * COUT];

    const int s = blockIdx.x / NBLK;
    const int blk = blockIdx.x - s * NBLK;
    const int ti = blk / NTB, tj = blk - ti * NTB;
    const int i0 = ti * TS - DIL, j0 = tj * TS - DIL;
    const int t = threadIdx.x;

    // ---- stage halo tile (vector loads, packed LDS writes) ----
    for (int loc = t; loc < TW * TW; loc += BDIM) {
        const int rr = loc / TW, cc = loc - rr * TW;
        const int gi = i0 + rr, gj = j0 + cc;
        const bool ok = (gi >= 0) & (gi < H_) & (gj >= 0) & (gj < W_);
        float lv[CSTR];
#pragma unroll
        for (int c = 0; c < CSTR; ++c) lv[c] = 0.f;
        if (ok) {
            if constexpr (FIRST) {
                const float* xg = (const float*)inv + (size_t)s * HW_;
                lv[0] = xg[(size_t)gi * W_ + gj];
            } else {
                const bf16* ing = (const bf16*)inv +
                                  ((size_t)s * HW_ + (size_t)gi * W_ + gj) * CIN;
                const float* ps = prevStats + s * 2 * CIN;
                if constexpr (CIN % 8 == 0) {
#pragma unroll
                    for (int qq = 0; qq < CIN / 8; ++qq) {
                        bf16x8 raw = ((const bf16x8*)ing)[qq];
#pragma unroll
                        for (int u = 0; u < 8; ++u) {
                            const int ci = 8 * qq + u;
                            lv[ci] = fmaxf(((float)raw[u] - ps[2 * ci]) * ps[2 * ci + 1], 0.f);
                        }
                    }
                } else {
#pragma unroll
                    for (int qq = 0; qq < CIN / 4; ++qq) {
                        bf16x4 raw = ((const bf16x4*)ing)[qq];
#pragma unroll
                        for (int u = 0; u < 4; ++u) {
                            const int ci = 4 * qq + u;
                            lv[ci] = fmaxf(((float)raw[u] - ps[2 * ci]) * ps[2 * ci + 1], 0.f);
                        }
                    }
                }
            }
        }
        bf16* lp = tile + loc * CSTR;
#pragma unroll
        for (int g = 0; g < CSTR / 4; ++g) {
            bf16x4 pk = { (bf16)lv[4 * g], (bf16)lv[4 * g + 1],
                          (bf16)lv[4 * g + 2], (bf16)lv[4 * g + 3] };
            *(bf16x4*)(lp + 4 * g) = pk;
        }
    }
    __syncthreads();

    // ---- MFMA K-loop, software-pipelined 1 ks ahead ----
    const int wave = t >> 6, lane = t & 63, q = lane >> 4, ln = lane & 15;
    f32x4 acc[4][NT];
#pragma unroll
    for (int mt = 0; mt < 4; ++mt)
#pragma unroll
        for (int u = 0; u < NT; ++u) acc[mt][u] = (f32x4){0.f, 0.f, 0.f, 0.f};

    auto aOff = [&](int ks) -> int {
        int k0 = ks * 32 + q * 8;
        int tap = k0 / CINP;
        int ci0 = k0 - tap * CINP;
        if (tap > 8) { tap = 0; ci0 = 0; }   // padded k: B rows are zero
        const int ky = tap / 3, kx = tap - 3 * ky;
        return (ky * DIL * TW + kx * DIL) * CSTR + ci0;
    };

    bf16x8 bfr[NT], bfrN[NT];
    bf16x8 af[4], afN[4];
#pragma unroll
    for (int u = 0; u < NT; ++u)
        bfr[u] = *(const bf16x8*)&wp[(u * 16 + ln) * KPP + q * 8];
    {
        const int ao = aOff(0);
#pragma unroll
        for (int mt = 0; mt < 4; ++mt)
            af[mt] = *(const bf16x8*)&tile[((wave * 4 + mt) * TW + ln) * CSTR + ao];
    }

#pragma unroll
    for (int ks = 0; ks < KS; ++ks) {
        if (ks + 1 < KS) {
#pragma unroll
            for (int u = 0; u < NT; ++u)
                bfrN[u] = *(const bf16x8*)&wp[(u * 16 + ln) * KPP + (ks + 1) * 32 + q * 8];
            const int ao = aOff(ks + 1);
#pragma unroll
            for (int mt = 0; mt < 4; ++mt)
                afN[mt] = *(const bf16x8*)&tile[((wave * 4 + mt) * TW + ln) * CSTR + ao];
        }
#pragma unroll
        for (int mt = 0; mt < 4; ++mt)
#pragma unroll
            for (int u = 0; u < NT; ++u)
                acc[mt][u] = __builtin_amdgcn_mfma_f32_16x16x32_bf16(
                    af[mt], bfr[u], acc[mt][u], 0, 0, 0);
#pragma unroll
        for (int u = 0; u < NT; ++u) bfr[u] = bfrN[u];
#pragma unroll
        for (int mt = 0; mt < 4; ++mt) af[mt] = afN[mt];
    }

    // ---- bias + per-block stats via cross-lane reduce ----
#pragma unroll
    for (int u = 0; u < NT; ++u) {
        const int n = u * 16 + ln;
        const float bv = (n < COUT) ? bias[n] : 0.f;
        float s1 = 0.f, s2 = 0.f;
#pragma unroll
        for (int mt = 0; mt < 4; ++mt)
#pragma unroll
            for (int r = 0; r < 4; ++r) {
                const float v = acc[mt][u][r] + bv;
                acc[mt][u][r] = v;
                s1 += v; s2 += v * v;
            }
        s1 += __shfl_xor(s1, 16); s1 += __shfl_xor(s1, 32);
        s2 += __shfl_xor(s2, 16); s2 += __shfl_xor(s2, 32);
        if (lane < 16 && n < COUT) { sred[wave][n] = s1; sred[wave][COUT + n] = s2; }
    }
    __syncthreads();   // K-loop tile reads complete + sred visible

    // atomically accumulate this block's sums (device scope)
    if (t < 2 * COUT) {
        const float v = sred[0][t] + sred[1][t] + sred[2][t] + sred[3][t];
        atomicAdd(&accL[s * 48 + t], v);
    }

    // ---- out-stage into LDS (reuse tile) ----
    bf16* ost = tile;   // 256*COUT bf16 <= tile capacity for all layers
#pragma unroll
    for (int u = 0; u < NT; ++u) {
        const int n = u * 16 + ln;
        if (n < COUT) {
#pragma unroll
            for (int mt = 0; mt < 4; ++mt)
#pragma unroll
                for (int r = 0; r < 4; ++r) {
                    const int pl = (wave * 4 + mt) * 16 + q * 4 + r;
                    ost[pl * COUT + n] = (bf16)acc[mt][u][r];
                }
        }
    }
    __threadfence();   // each writer: its atomicAdd visible device-wide
    __syncthreads();   // ost complete + all block atomics fenced

    // ---- coalesced global stores ----
    const int lr = t >> 4, lc = t & 15;
    bf16* yp = y + (size_t)s * HW_ * COUT +
               ((size_t)(ti * TS + lr) * W_ + (tj * TS + lc)) * COUT;
    const bf16* sp = ost + t * COUT;
    if constexpr (COUT % 8 == 0) {
#pragma unroll
        for (int g = 0; g < COUT / 8; ++g)
            ((bf16x8*)yp)[g] = ((const bf16x8*)sp)[g];
    } else {
#pragma unroll
        for (int g = 0; g < COUT / 4; ++g)
            ((bf16x4*)yp)[g] = ((const bf16x4*)sp)[g];
    }

    // ---- last block per sample computes mean/invstd ----
    if (t == 0) {
        const unsigned old = atomicAdd(&cntL[s], 1u);
        if (old == (unsigned)(NBLK - 1)) {
            for (int co = 0; co < COUT; ++co) {
                const float s1 = atomicAdd(&accL[s * 48 + co], 0.f);
                const float s2 = atomicAdd(&accL[s * 48 + COUT + co], 0.f);
                const float m = s1 / (float)HW_;
                const float var = s2 / (float)HW_ - m * m;
                statsL[(s * COUT + co) * 2 + 0] = m;
                statsL[(s * COUT + co) * 2 + 1] = rsqrtf(var + 1e-5f);
            }
        }
    }
}

// ---------------------------------------------------------------------------
// Merged head: conv2 (24->6, dil 1, MFMA, folded norm of L5) + channel
// softmax (weights kept in registers) + fused Sauvola via LOCAL 35x35 fp32
// integral images of x and x^2 in LDS. f never touches global memory.
// ---------------------------------------------------------------------------
__global__ __launch_bounds__(BDIM) void conv2_sauvola(
    const bf16* __restrict__ in, const float* __restrict__ prevStats,
    const bf16* __restrict__ wp, const float* __restrict__ bias,
    const float* __restrict__ x,
    const float* __restrict__ kArr, const float* __restrict__ RArr,
    const float* __restrict__ alphaP, float* __restrict__ outp)
{
    constexpr int CIN = 24, CINP = 24, COUT = 6, DIL = 1;
    constexpr int TW = TS + 2 * DIL;      // 18
    constexpr int KPP = 232, KS = 7, CSTR = 24;
    constexpr int R9 = 9;                 // max window radius (19>>1)
    constexpr int TSW = TS + 2 * R9;      // 34
    constexpr int PSTR = 36;              // integral-image LDS row stride
    __shared__ __align__(16) bf16 tile[TW * TW * CSTR];   // 15552 B; slog after
    __shared__ float I1[35 * PSTR];                        // 5040 B
    __shared__ float I2[35 * PSTR];                        // 5040 B

    const int s = blockIdx.x / NBLK;
    const int blk = blockIdx.x - s * NBLK;
    const int ti = blk / NTB, tj = blk - ti * NTB;
    const int i0 = ti * TS - DIL, j0 = tj * TS - DIL;
    const int is0 = ti * TS - R9, js0 = tj * TS - R9;
    const int t = threadIdx.x;
    const float* xs = x + (size_t)s * HW_;

    // ---- stage conv2 tile (normed bf16) ----
    const float* ps = prevStats + s * 2 * CIN;
    for (int loc = t; loc < TW * TW; loc += BDIM) {
        const int rr = loc / TW, cc = loc - rr * TW;
        const int gi = i0 + rr, gj = j0 + cc;
        const bool ok = (gi >= 0) & (gi < H_) & (gj >= 0) & (gj < W_);
        float lv[CSTR];
#pragma unroll
        for (int c = 0; c < CSTR; ++c) lv[c] = 0.f;
        if (ok) {
            const bf16* ing = in + ((size_t)s * HW_ + (size_t)gi * W_ + gj) * CIN;
#pragma unroll
            for (int qq = 0; qq < CIN / 8; ++qq) {
                bf16x8 raw = ((const bf16x8*)ing)[qq];
#pragma unroll
                for (int u = 0; u < 8; ++u) {
                    const int ci = 8 * qq + u;
                    lv[ci] = fmaxf(((float)raw[u] - ps[2 * ci]) * ps[2 * ci + 1], 0.f);
                }
            }
        }
        bf16* lp = tile + loc * CSTR;
#pragma unroll
        for (int g = 0; g < CSTR / 4; ++g) {
            bf16x4 pk = { (bf16)lv[4 * g], (bf16)lv[4 * g + 1],
                          (bf16)lv[4 * g + 2], (bf16)lv[4 * g + 3] };
            *(bf16x4*)(lp + 4 * g) = pk;
        }
    }
    // ---- stage 34x34 x-halo into I1/I2 (rows/cols 1..34); zero row0/col0 ----
    for (int loc = t; loc < TSW * TSW; loc += BDIM) {
        const int rr = loc / TSW, cc = loc - rr * TSW;
        const int gi = is0 + rr, gj = js0 + cc;
        float v = 0.f;
        if ((gi >= 0) & (gi < H_) & (gj >= 0) & (gj < W_))
            v = xs[(size_t)gi * W_ + gj];
        I1[(rr + 1) * PSTR + cc + 1] = v;
        I2[(rr + 1) * PSTR + cc + 1] = v * v;
    }
    for (int idx = t; idx < 2 * (35 + 34); idx += BDIM) {
        const int arr = idx / (35 + 34);
        const int r2 = idx - arr * (35 + 34);
        float* P = arr ? I2 : I1;
        if (r2 < 35) P[r2] = 0.f;                       // row 0
        else P[(r2 - 35 + 1) * PSTR] = 0.f;             // col 0, rows 1..34
    }
    __syncthreads();

    // ---- conv2 MFMA K-loop (pipelined) ----
    const int wave = t >> 6, lane = t & 63, q = lane >> 4, ln = lane & 15;
    f32x4 acc[4];
#pragma unroll
    for (int mt = 0; mt < 4; ++mt) acc[mt] = (f32x4){0.f, 0.f, 0.f, 0.f};

    auto aOff = [&](int ks) -> int {
        int k0 = ks * 32 + q * 8;
        int tap = k0 / CINP;
        int ci0 = k0 - tap * CINP;
        if (tap > 8) { tap = 0; ci0 = 0; }
        const int ky = tap / 3, kx = tap - 3 * ky;
        return (ky * DIL * TW + kx * DIL) * CSTR + ci0;
    };

    bf16x8 bfr, bfrN;
    bf16x8 af[4], afN[4];
    bfr = *(const bf16x8*)&wp[ln * KPP + q * 8];
    {
        const int ao = aOff(0);
#pragma unroll
        for (int mt = 0; mt < 4; ++mt)
            af[mt] = *(const bf16x8*)&tile[((wave * 4 + mt) * TW + ln) * CSTR + ao];
    }
#pragma unroll
    for (int ks = 0; ks < KS; ++ks) {
        if (ks + 1 < KS) {
            bfrN = *(const bf16x8*)&wp[ln * KPP + (ks + 1) * 32 + q * 8];
            const int ao = aOff(ks + 1);
#pragma unroll
            for (int mt = 0; mt < 4; ++mt)
                afN[mt] = *(const bf16x8*)&tile[((wave * 4 + mt) * TW + ln) * CSTR + ao];
        }
#pragma unroll
        for (int mt = 0; mt < 4; ++mt)
            acc[mt] = __builtin_amdgcn_mfma_f32_16x16x32_bf16(af[mt], bfr, acc[mt], 0, 0, 0);
        bfr = bfrN;
#pragma unroll
        for (int mt = 0; mt < 4; ++mt) af[mt] = afN[mt];
    }
    __syncthreads();   // done reading tile -> reuse as logits

    // ---- phase A: logits -> slog (tile) ; row-prefix I1/I2 (t<68) ----
    float* slog = (float*)tile;            // 256*6*4 = 6144 B <= 15552 B
    const float bv = (ln < COUT) ? bias[ln] : 0.f;
#pragma unroll
    for (int mt = 0; mt < 4; ++mt)
#pragma unroll
        for (int r = 0; r < 4; ++r)
            if (ln < COUT) {
                const int pl = (wave * 4 + mt) * 16 + q * 4 + r;
                slog[pl * COUT + ln] = acc[mt][r] + bv;
            }
    if (t < 68) {
        float* P = (t >= 34) ? I2 : I1;
        float* row = P + ((t >= 34 ? t - 34 : t) + 1) * PSTR;
        float a = 0.f;
#pragma unroll 2
        for (int c = 1; c <= TSW; ++c) { a += row[c]; row[c] = a; }
    }
    __syncthreads();

    // ---- phase B: col-prefix (t<68) + per-thread softmax from slog ----
    if (t < 68) {
        float* P = (t >= 34) ? I2 : I1;
        const int c = (t >= 34 ? t - 34 : t) + 1;
        float a = 0.f;
#pragma unroll 2
        for (int r = 1; r <= TSW; ++r) { a += P[r * PSTR + c]; P[r * PSTR + c] = a; }
    }
    float e[COUT];
    {
        float mx = slog[t * COUT];
#pragma unroll
        for (int co = 1; co < COUT; ++co) mx = fmaxf(mx, slog[t * COUT + co]);
        float sm = 0.f;
#pragma unroll
        for (int co = 0; co < COUT; ++co) { e[co] = __expf(slog[t * COUT + co] - mx); sm += e[co]; }
        const float inv = 1.f / sm;
#pragma unroll
        for (int co = 0; co < COUT; ++co) e[co] *= inv;
    }
    __syncthreads();   // col prefix complete before lookups

    // ---- phase C: Sauvola per pixel (f = e[] in registers) ----
    const int lr = t >> 4, lc = t & 15;
    const int gi = ti * TS + lr, gj = tj * TS + lc;
    const float xv = xs[(size_t)gi * W_ + gj];
    const float alpha = alphaP[0];

    const int wins[6] = {3, 5, 7, 11, 15, 19};
    float th1 = 0.f;
#pragma unroll
    for (int wi = 0; wi < 6; ++wi) {
        const int r = wins[wi] >> 1;
        const int r0 = max(gi - r, 0), r1i = min(gi + r, H_ - 1);
        const int c0 = max(gj - r, 0), c1 = min(gj + r, W_ - 1);
        const float invc = 1.f / (float)((r1i - r0 + 1) * (c1 - c0 + 1));
        const int top = lr + R9 - r, bot = lr + R9 + r + 1;
        const int lef = lc + R9 - r, rig = lc + R9 + r + 1;
        const float s1 = I1[bot * PSTR + rig] - I1[top * PSTR + rig]
                       - I1[bot * PSTR + lef] + I1[top * PSTR + lef];
        const float s2 = I2[bot * PSTR + rig] - I2[top * PSTR + rig]
                       - I2[bot * PSTR + lef] + I2[top * PSTR + lef];
        const float Ex = s1 * invc;
        const float Ex2 = s2 * invc;
        const float dev = sqrtf(fmaxf(Ex2 - Ex * Ex, 1e-6f));
        const float th = Ex * (1.f + kArr[wi] * (dev / RArr[wi] - 1.f));
        th1 = fmaf(e[wi], th, th1);
    }
    outp[(size_t)s * HW_ + (size_t)gi * W_ + gj] = (xv - th1) * alpha;
}

// ---------------------------------------------------------------------------
extern "C" void kernel_launch(void* const* d_in, const int* in_sizes, int n_in,
                              void* d_out, int out_size, void* d_ws, size_t ws_size,
                              hipStream_t stream) {
    const float* x   = (const float*)d_in[0];
    const float* w0  = (const float*)d_in[1];  const float* b0 = (const float*)d_in[2];
    const float* w1  = (const float*)d_in[3];  const float* b1 = (const float*)d_in[4];
    const float* w2  = (const float*)d_in[5];  const float* b2 = (const float*)d_in[6];
    const float* w3  = (const float*)d_in[7];  const float* b3 = (const float*)d_in[8];
    const float* w4  = (const float*)d_in[9];  const float* b4 = (const float*)d_in[10];
    const float* w5  = (const float*)d_in[11]; const float* b5 = (const float*)d_in[12];
    const float* wf  = (const float*)d_in[13]; const float* bf = (const float*)d_in[14];
    const float* kA  = (const float*)d_in[15];
    const float* RA  = (const float*)d_in[16];
    const float* alp = (const float*)d_in[17];
    float* out = (float*)d_out;
    (void)n_in; (void)in_sizes; (void)out_size;

    // ---- choose samples-per-launch from ws_size (deterministic) ----
    auto need = [](int nb) -> size_t {
        size_t o = 0;
        auto al = [&](size_t bytes) { o += (bytes + 255) & ~(size_t)255; };
        al((size_t)nb * HW_ * 20 * 2);          // bufA (bf16)
        al((size_t)nb * HW_ * 24 * 2);          // bufB (bf16)
        al(1664 * 2); al(1664 * 2); al(1664 * 2); al(2688 * 2);
        al(5376 * 2); al(7424 * 2); al(3712 * 2);
        al(6 * LSTRIDE * 4);                    // acc
        al(24 * 4);                             // cnt
        al(6 * LSTRIDE * 4);                    // stats
        return o;
    };
    int nb = 1;
    if (ws_size >= need(4)) nb = 4;
    else if (ws_size >= need(2)) nb = 2;

    char* ws = (char*)d_ws;
    size_t off = 0;
    auto alloc = [&](size_t bytes) -> void* {
        void* p = ws + off;
        off += (bytes + 255) & ~(size_t)255;
        return p;
    };
    bf16*  bufA = (bf16*)alloc((size_t)nb * HW_ * 20 * 2);
    bf16*  bufB = (bf16*)alloc((size_t)nb * HW_ * 24 * 2);
    bf16* r0 = (bf16*)alloc(1664 * 2);
    bf16* r1 = (bf16*)alloc(1664 * 2);
    bf16* r2 = (bf16*)alloc(1664 * 2);
    bf16* r3 = (bf16*)alloc(2688 * 2);
    bf16* r4 = (bf16*)alloc(5376 * 2);
    bf16* r5 = (bf16*)alloc(7424 * 2);
    bf16* rf = (bf16*)alloc(3712 * 2);
    float*    acc   = (float*)alloc(6 * LSTRIDE * 4);
    unsigned* cnt   = (unsigned*)alloc(24 * 4);
    float*    stats = (float*)alloc(6 * LSTRIDE * 4);

    const dim3 blk(BDIM);
    const int cg = nb * NBLK;

    repack_all<<<7, blk, 0, stream>>>(w0, w1, w2, w3, w4, w5, wf,
                                      r0, r1, r2, r3, r4, r5, rf);

    for (int it = 0; it < B_ / nb; ++it) {
        const float* xc   = x   + (size_t)it * nb * HW_;
        float*       outc = out + (size_t)it * nb * HW_;

        zero_stats<<<1, blk, 0, stream>>>(acc, cnt);

        conv_mfma<1, 8, 4, 1, true><<<cg, blk, 0, stream>>>(
            xc, nullptr, r0, b0, bufA,
            acc + 0 * LSTRIDE, cnt + 0 * 4, stats + 0 * LSTRIDE);

        conv_mfma<4, 8, 8, 2, false><<<cg, blk, 0, stream>>>(
            bufA, stats + 0 * LSTRIDE, r1, b1, bufB,
            acc + 1 * LSTRIDE, cnt + 1 * 4, stats + 1 * LSTRIDE);

        conv_mfma<8, 8, 12, 2, false><<<cg, blk, 0, stream>>>(
            bufB, stats + 1 * LSTRIDE, r2, b2, bufA,
            acc + 2 * LSTRIDE, cnt + 2 * 4, stats + 2 * LSTRIDE);

        conv_mfma<12, 16, 16, 2, false><<<cg, blk, 0, stream>>>(
            bufA, stats + 2 * LSTRIDE, r3, b3, bufB,
            acc + 3 * LSTRIDE, cnt + 3 * 4, stats + 3 * LSTRIDE);

        conv_mfma<16, 16, 20, 2, false><<<cg, blk, 0, stream>>>(
            bufB, stats + 3 * LSTRIDE, r4, b4, bufA,
            acc + 4 * LSTRIDE, cnt + 4 * 4, stats + 4 * LSTRIDE);

        conv_mfma<20, 24, 24, 2, false><<<cg, blk, 0, stream>>>(
            bufA, stats + 4 * LSTRIDE, r5, b5, bufB,
            acc + 5 * LSTRIDE, cnt + 5 * 4, stats + 5 * LSTRIDE);

        conv2_sauvola<<<cg, blk, 0, stream>>>(
            bufB, stats + 5 * LSTRIDE, rf, bf, xc, kA, RA, alp, outc);
    }
}

// Round 12
// 416.011 us; speedup vs baseline: 15.1020x; 15.1020x over previous
//
#include <hip/hip_runtime.h>
#include <math.h>

#define BDIM 256
typedef __bf16 bf16;
typedef __bf16 bf16x4 __attribute__((ext_vector_type(4)));
typedef __bf16 bf16x8 __attribute__((ext_vector_type(8)));
typedef float f32x4 __attribute__((ext_vector_type(4)));

constexpr int B_ = 4, H_ = 768, W_ = 768;
constexpr int HW_ = H_ * W_;                 // 589824
constexpr int TS = 16;                       // spatial tile 16x16 px/block
constexpr int NTB = W_ / TS;                 // 48
constexpr int NBLK = HW_ / (TS * TS);        // 2304 blocks per sample

// scratch carved from the TAIL of d_out (written before read each iteration;
// the final conv2_sauvola of the last chunk overwrites it after last use):
constexpr int PMAX_FLOATS = 4 * NBLK * 48;          // 442368
constexpr int OUT_ELEMS   = B_ * HW_;               // 2359296

// ---------------------------------------------------------------------------
// Weight repack: [COUT][CIN][3][3] fp32 -> padded bf16 [NT*16][KPP],
// k = tap*CINP + ci, zero everywhere outside (n<COUT, tap<9, ci<CIN).
// ---------------------------------------------------------------------------
__device__ void repack_one(const float* __restrict__ src, bf16* __restrict__ dst,
                           int CIN, int CINP, int COUT, int NT16, int KPP)
{
    const int n_ = NT16 * KPP;
    for (int idx = threadIdx.x; idx < n_; idx += BDIM) {
        const int n = idx / KPP, k = idx - n * KPP;
        const int tap = k / CINP, ci = k - tap * CINP;
        float v = 0.f;
        if (n < COUT && tap < 9 && ci < CIN)
            v = src[(n * CIN + ci) * 9 + tap];
        dst[idx] = (bf16)v;
    }
}

__global__ __launch_bounds__(BDIM) void repack_all(
    const float* w0, const float* w1, const float* w2, const float* w3,
    const float* w4, const float* w5, const float* wf,
    bf16* r0, bf16* r1, bf16* r2, bf16* r3, bf16* r4, bf16* r5, bf16* rf)
{
    switch (blockIdx.x) {
        case 0: repack_one(w0, r0, 1,  8,  4,  16, 104); break;
        case 1: repack_one(w1, r1, 4,  8,  8,  16, 104); break;
        case 2: repack_one(w2, r2, 8,  8,  12, 16, 104); break;
        case 3: repack_one(w3, r3, 12, 16, 16, 16, 168); break;
        case 4: repack_one(w4, r4, 16, 16, 20, 32, 168); break;
        case 5: repack_one(w5, r5, 20, 24, 24, 32, 232); break;
        case 6: repack_one(wf, rf, 24, 24, 6,  16, 232); break;
    }
}

// ---------------------------------------------------------------------------
// bf16-MFMA conv 3x3 (dilated, SAME) + bias, NHWC, nb samples (grid=nb*NBLK).
// Halo tile staged channel-innermost bf16 (prev-layer norm+relu fused, OOB=0).
// GEMM: M=256 px, N=COUT (NT x16), K=9*CINP (KS x32). fp32 accum.
// Weights from global/L1; K-loop software-pipelined one ks ahead.
// NOTE R11 lesson: NO device-scope atomics/__threadfence here — a per-block
// fence forces an L2 writeback on gfx950 (WRITE_SIZE doubled, 15x slowdown).
// Stats go to per-block partials + a tiny reduce kernel instead.
// ---------------------------------------------------------------------------
template <int CIN, int CINP, int COUT, int DIL, bool FIRST>
__global__ __launch_bounds__(BDIM) void conv_mfma(
    const void* __restrict__ inv,        // FIRST: fp32 x; else bf16 y_prev
    const float* __restrict__ prevStats, // [nb][CIN][2] (mean, invstd)
    const bf16* __restrict__ wp,         // packed [NT*16][KPP]
    const float* __restrict__ bias,      // [COUT] fp32
    bf16* __restrict__ y,                // [nb][H][W][COUT]
    float* __restrict__ partials)        // [nb][NBLK][2*COUT]
{
    constexpr int TW = TS + 2 * DIL;
    constexpr int KP = ((9 * CINP + 31) / 32) * 32;
    constexpr int KPP = KP + 8;
    constexpr int NT = (COUT + 15) / 16;
    constexpr int KS = KP / 32;
    constexpr int CSTR = (CINP == 16) ? 24 : CINP;   // multiple of 8 (b128 align)
    __shared__ __align__(16) bf16 tile[TW * TW * CSTR];
    __shared__ float sred[4][2 * COUT];

    const int s = blockIdx.x / NBLK;
    const int blk = blockIdx.x - s * NBLK;
    const int ti = blk / NTB, tj = blk - ti * NTB;
    const int i0 = ti * TS - DIL, j0 = tj * TS - DIL;
    const int t = threadIdx.x;

    // ---- stage halo tile (vector loads, packed LDS writes) ----
    for (int loc = t; loc < TW * TW; loc += BDIM) {
        const int rr = loc / TW, cc = loc - rr * TW;
        const int gi = i0 + rr, gj = j0 + cc;
        const bool ok = (gi >= 0) & (gi < H_) & (gj >= 0) & (gj < W_);
        float lv[CSTR];
#pragma unroll
        for (int c = 0; c < CSTR; ++c) lv[c] = 0.f;
        if (ok) {
            if constexpr (FIRST) {
                const float* xg = (const float*)inv + (size_t)s * HW_;
                lv[0] = xg[(size_t)gi * W_ + gj];
            } else {
                const bf16* ing = (const bf16*)inv +
                                  ((size_t)s * HW_ + (size_t)gi * W_ + gj) * CIN;
                const float* ps = prevStats + s * 2 * CIN;
                if constexpr (CIN % 8 == 0) {
#pragma unroll
                    for (int qq = 0; qq < CIN / 8; ++qq) {
                        bf16x8 raw = ((const bf16x8*)ing)[qq];
#pragma unroll
                        for (int u = 0; u < 8; ++u) {
                            const int ci = 8 * qq + u;
                            lv[ci] = fmaxf(((float)raw[u] - ps[2 * ci]) * ps[2 * ci + 1], 0.f);
                        }
                    }
                } else {
#pragma unroll
                    for (int qq = 0; qq < CIN / 4; ++qq) {
                        bf16x4 raw = ((const bf16x4*)ing)[qq];
#pragma unroll
                        for (int u = 0; u < 4; ++u) {
                            const int ci = 4 * qq + u;
                            lv[ci] = fmaxf(((float)raw[u] - ps[2 * ci]) * ps[2 * ci + 1], 0.f);
                        }
                    }
                }
            }
        }
        bf16* lp = tile + loc * CSTR;
#pragma unroll
        for (int g = 0; g < CSTR / 4; ++g) {
            bf16x4 pk = { (bf16)lv[4 * g], (bf16)lv[4 * g + 1],
                          (bf16)lv[4 * g + 2], (bf16)lv[4 * g + 3] };
            *(bf16x4*)(lp + 4 * g) = pk;
        }
    }
    __syncthreads();

    // ---- MFMA K-loop, software-pipelined 1 ks ahead ----
    const int wave = t >> 6, lane = t & 63, q = lane >> 4, ln = lane & 15;
    f32x4 acc[4][NT];
#pragma unroll
    for (int mt = 0; mt < 4; ++mt)
#pragma unroll
        for (int u = 0; u < NT; ++u) acc[mt][u] = (f32x4){0.f, 0.f, 0.f, 0.f};

    auto aOff = [&](int ks) -> int {
        int k0 = ks * 32 + q * 8;
        int tap = k0 / CINP;
        int ci0 = k0 - tap * CINP;
        if (tap > 8) { tap = 0; ci0 = 0; }   // padded k: B rows are zero
        const int ky = tap / 3, kx = tap - 3 * ky;
        return (ky * DIL * TW + kx * DIL) * CSTR + ci0;
    };

    bf16x8 bfr[NT], bfrN[NT];
    bf16x8 af[4], afN[4];
#pragma unroll
    for (int u = 0; u < NT; ++u)
        bfr[u] = *(const bf16x8*)&wp[(u * 16 + ln) * KPP + q * 8];
    {
        const int ao = aOff(0);
#pragma unroll
        for (int mt = 0; mt < 4; ++mt)
            af[mt] = *(const bf16x8*)&tile[((wave * 4 + mt) * TW + ln) * CSTR + ao];
    }

#pragma unroll
    for (int ks = 0; ks < KS; ++ks) {
        if (ks + 1 < KS) {
#pragma unroll
            for (int u = 0; u < NT; ++u)
                bfrN[u] = *(const bf16x8*)&wp[(u * 16 + ln) * KPP + (ks + 1) * 32 + q * 8];
            const int ao = aOff(ks + 1);
#pragma unroll
            for (int mt = 0; mt < 4; ++mt)
                afN[mt] = *(const bf16x8*)&tile[((wave * 4 + mt) * TW + ln) * CSTR + ao];
        }
#pragma unroll
        for (int mt = 0; mt < 4; ++mt)
#pragma unroll
            for (int u = 0; u < NT; ++u)
                acc[mt][u] = __builtin_amdgcn_mfma_f32_16x16x32_bf16(
                    af[mt], bfr[u], acc[mt][u], 0, 0, 0);
#pragma unroll
        for (int u = 0; u < NT; ++u) bfr[u] = bfrN[u];
#pragma unroll
        for (int mt = 0; mt < 4; ++mt) af[mt] = afN[mt];
    }

    // ---- bias + stats (registers), sred ----
#pragma unroll
    for (int u = 0; u < NT; ++u) {
        const int n = u * 16 + ln;
        const float bv = (n < COUT) ? bias[n] : 0.f;
        float s1 = 0.f, s2 = 0.f;
#pragma unroll
        for (int mt = 0; mt < 4; ++mt)
#pragma unroll
            for (int r = 0; r < 4; ++r) {
                const float v = acc[mt][u][r] + bv;
                acc[mt][u][r] = v;
                s1 += v; s2 += v * v;
            }
        s1 += __shfl_xor(s1, 16); s1 += __shfl_xor(s1, 32);
        s2 += __shfl_xor(s2, 16); s2 += __shfl_xor(s2, 32);
        if (lane < 16 && n < COUT) { sred[wave][n] = s1; sred[wave][COUT + n] = s2; }
    }
    __syncthreads();   // K-loop tile reads complete + sred visible
    if (t < 2 * COUT) {
        partials[((size_t)s * NBLK + blk) * (2 * COUT) + t] =
            sred[0][t] + sred[1][t] + sred[2][t] + sred[3][t];
    }

    // ---- out-stage into LDS (reuse tile), then coalesced global stores ----
    bf16* ost = tile;   // 256*COUT bf16 <= tile capacity for all layers
#pragma unroll
    for (int u = 0; u < NT; ++u) {
        const int n = u * 16 + ln;
        if (n < COUT) {
#pragma unroll
            for (int mt = 0; mt < 4; ++mt)
#pragma unroll
                for (int r = 0; r < 4; ++r) {
                    const int pl = (wave * 4 + mt) * 16 + q * 4 + r;
                    ost[pl * COUT + n] = (bf16)acc[mt][u][r];
                }
        }
    }
    __syncthreads();

    const int lr = t >> 4, lc = t & 15;
    bf16* yp = y + (size_t)s * HW_ * COUT +
               ((size_t)(ti * TS + lr) * W_ + (tj * TS + lc)) * COUT;
    const bf16* sp = ost + t * COUT;
    if constexpr (COUT % 8 == 0) {
#pragma unroll
        for (int g = 0; g < COUT / 8; ++g)
            ((bf16x8*)yp)[g] = ((const bf16x8*)sp)[g];
    } else {
#pragma unroll
        for (int g = 0; g < COUT / 4; ++g)
            ((bf16x4*)yp)[g] = ((const bf16x4*)sp)[g];
    }
}

// ---------------------------------------------------------------------------
// Reduce per-block partials -> mean, invstd per (sample, channel)
// ---------------------------------------------------------------------------
template <int COUT>
__global__ __launch_bounds__(BDIM) void reduce_stats(
    const float* __restrict__ partials, float* __restrict__ stats)
{
    const int s = blockIdx.x / COUT;
    const int co = blockIdx.x - s * COUT;
    const float* P = partials + (size_t)s * NBLK * (2 * COUT);
    float s1 = 0.f, s2 = 0.f;
    for (int k = threadIdx.x; k < NBLK; k += BDIM) {
        const float* p = P + (size_t)k * (2 * COUT);
        s1 += p[co];
        s2 += p[COUT + co];
    }
#pragma unroll
    for (int off = 32; off; off >>= 1) {
        s1 += __shfl_xor(s1, off);
        s2 += __shfl_xor(s2, off);
    }
    __shared__ float l1[4], l2[4];
    const int lane = threadIdx.x & 63, wave = threadIdx.x >> 6;
    if (lane == 0) { l1[wave] = s1; l2[wave] = s2; }
    __syncthreads();
    if (threadIdx.x == 0) {
        float t1 = l1[0] + l1[1] + l1[2] + l1[3];
        float t2 = l2[0] + l2[1] + l2[2] + l2[3];
        float m = t1 / (float)HW_;
        float var = t2 / (float)HW_ - m * m;
        stats[((size_t)s * COUT + co) * 2 + 0] = m;
        stats[((size_t)s * COUT + co) * 2 + 1] = rsqrtf(var + 1e-5f);
    }
}

// ---------------------------------------------------------------------------
// Merged head: conv2 (24->6, dil 1, MFMA, folded norm of L5) + channel
// softmax (weights kept in registers) + fused Sauvola via LOCAL 35x35 fp32
// integral images of x and x^2 in LDS. f never touches global memory.
// ---------------------------------------------------------------------------
__global__ __launch_bounds__(BDIM) void conv2_sauvola(
    const bf16* __restrict__ in, const float* __restrict__ prevStats,
    const bf16* __restrict__ wp, const float* __restrict__ bias,
    const float* __restrict__ x,
    const float* __restrict__ kArr, const float* __restrict__ RArr,
    const float* __restrict__ alphaP, float* __restrict__ outp)
{
    constexpr int CIN = 24, CINP = 24, COUT = 6, DIL = 1;
    constexpr int TW = TS + 2 * DIL;      // 18
    constexpr int KPP = 232, KS = 7, CSTR = 24;
    constexpr int R9 = 9;                 // max window radius (19>>1)
    constexpr int TSW = TS + 2 * R9;      // 34
    constexpr int PSTR = 36;              // integral-image LDS row stride
    __shared__ __align__(16) bf16 tile[TW * TW * CSTR];   // 15552 B; slog after
    __shared__ float I1[35 * PSTR];                        // 5040 B
    __shared__ float I2[35 * PSTR];                        // 5040 B

    const int s = blockIdx.x / NBLK;
    const int blk = blockIdx.x - s * NBLK;
    const int ti = blk / NTB, tj = blk - ti * NTB;
    const int i0 = ti * TS - DIL, j0 = tj * TS - DIL;
    const int is0 = ti * TS - R9, js0 = tj * TS - R9;
    const int t = threadIdx.x;
    const float* xs = x + (size_t)s * HW_;

    // ---- stage conv2 tile (normed bf16) ----
    const float* ps = prevStats + s * 2 * CIN;
    for (int loc = t; loc < TW * TW; loc += BDIM) {
        const int rr = loc / TW, cc = loc - rr * TW;
        const int gi = i0 + rr, gj = j0 + cc;
        const bool ok = (gi >= 0) & (gi < H_) & (gj >= 0) & (gj < W_);
        float lv[CSTR];
#pragma unroll
        for (int c = 0; c < CSTR; ++c) lv[c] = 0.f;
        if (ok) {
            const bf16* ing = in + ((size_t)s * HW_ + (size_t)gi * W_ + gj) * CIN;
#pragma unroll
            for (int qq = 0; qq < CIN / 8; ++qq) {
                bf16x8 raw = ((const bf16x8*)ing)[qq];
#pragma unroll
                for (int u = 0; u < 8; ++u) {
                    const int ci = 8 * qq + u;
                    lv[ci] = fmaxf(((float)raw[u] - ps[2 * ci]) * ps[2 * ci + 1], 0.f);
                }
            }
        }
        bf16* lp = tile + loc * CSTR;
#pragma unroll
        for (int g = 0; g < CSTR / 4; ++g) {
            bf16x4 pk = { (bf16)lv[4 * g], (bf16)lv[4 * g + 1],
                          (bf16)lv[4 * g + 2], (bf16)lv[4 * g + 3] };
            *(bf16x4*)(lp + 4 * g) = pk;
        }
    }
    // ---- stage 34x34 x-halo into I1/I2 (rows/cols 1..34); zero row0/col0 ----
    for (int loc = t; loc < TSW * TSW; loc += BDIM) {
        const int rr = loc / TSW, cc = loc - rr * TSW;
        const int gi = is0 + rr, gj = js0 + cc;
        float v = 0.f;
        if ((gi >= 0) & (gi < H_) & (gj >= 0) & (gj < W_))
            v = xs[(size_t)gi * W_ + gj];
        I1[(rr + 1) * PSTR + cc + 1] = v;
        I2[(rr + 1) * PSTR + cc + 1] = v * v;
    }
    for (int idx = t; idx < 2 * (35 + 34); idx += BDIM) {
        const int arr = idx / (35 + 34);
        const int r2 = idx - arr * (35 + 34);
        float* P = arr ? I2 : I1;
        if (r2 < 35) P[r2] = 0.f;                       // row 0
        else P[(r2 - 35 + 1) * PSTR] = 0.f;             // col 0, rows 1..34
    }
    __syncthreads();

    // ---- conv2 MFMA K-loop (pipelined) ----
    const int wave = t >> 6, lane = t & 63, q = lane >> 4, ln = lane & 15;
    f32x4 acc[4];
#pragma unroll
    for (int mt = 0; mt < 4; ++mt) acc[mt] = (f32x4){0.f, 0.f, 0.f, 0.f};

    auto aOff = [&](int ks) -> int {
        int k0 = ks * 32 + q * 8;
        int tap = k0 / CINP;
        int ci0 = k0 - tap * CINP;
        if (tap > 8) { tap = 0; ci0 = 0; }
        const int ky = tap / 3, kx = tap - 3 * ky;
        return (ky * DIL * TW + kx * DIL) * CSTR + ci0;
    };

    bf16x8 bfr, bfrN;
    bf16x8 af[4], afN[4];
    bfr = *(const bf16x8*)&wp[ln * KPP + q * 8];
    {
        const int ao = aOff(0);
#pragma unroll
        for (int mt = 0; mt < 4; ++mt)
            af[mt] = *(const bf16x8*)&tile[((wave * 4 + mt) * TW + ln) * CSTR + ao];
    }
#pragma unroll
    for (int ks = 0; ks < KS; ++ks) {
        if (ks + 1 < KS) {
            bfrN = *(const bf16x8*)&wp[ln * KPP + (ks + 1) * 32 + q * 8];
            const int ao = aOff(ks + 1);
#pragma unroll
            for (int mt = 0; mt < 4; ++mt)
                afN[mt] = *(const bf16x8*)&tile[((wave * 4 + mt) * TW + ln) * CSTR + ao];
        }
#pragma unroll
        for (int mt = 0; mt < 4; ++mt)
            acc[mt] = __builtin_amdgcn_mfma_f32_16x16x32_bf16(af[mt], bfr, acc[mt], 0, 0, 0);
        bfr = bfrN;
#pragma unroll
        for (int mt = 0; mt < 4; ++mt) af[mt] = afN[mt];
    }
    __syncthreads();   // done reading tile -> reuse as logits

    // ---- phase A: logits -> slog (tile) ; row-prefix I1/I2 (t<68) ----
    float* slog = (float*)tile;            // 256*6*4 = 6144 B <= 15552 B
    const float bv = (ln < COUT) ? bias[ln] : 0.f;
#pragma unroll
    for (int mt = 0; mt < 4; ++mt)
#pragma unroll
        for (int r = 0; r < 4; ++r)
            if (ln < COUT) {
                const int pl = (wave * 4 + mt) * 16 + q * 4 + r;
                slog[pl * COUT + ln] = acc[mt][r] + bv;
            }
    if (t < 68) {
        float* P = (t >= 34) ? I2 : I1;
        float* row = P + ((t >= 34 ? t - 34 : t) + 1) * PSTR;
        float a = 0.f;
#pragma unroll 2
        for (int c = 1; c <= TSW; ++c) { a += row[c]; row[c] = a; }
    }
    __syncthreads();

    // ---- phase B: col-prefix (t<68) + per-thread softmax from slog ----
    if (t < 68) {
        float* P = (t >= 34) ? I2 : I1;
        const int c = (t >= 34 ? t - 34 : t) + 1;
        float a = 0.f;
#pragma unroll 2
        for (int r = 1; r <= TSW; ++r) { a += P[r * PSTR + c]; P[r * PSTR + c] = a; }
    }
    float e[COUT];
    {
        float mx = slog[t * COUT];
#pragma unroll
        for (int co = 1; co < COUT; ++co) mx = fmaxf(mx, slog[t * COUT + co]);
        float sm = 0.f;
#pragma unroll
        for (int co = 0; co < COUT; ++co) { e[co] = __expf(slog[t * COUT + co] - mx); sm += e[co]; }
        const float inv = 1.f / sm;
#pragma unroll
        for (int co = 0; co < COUT; ++co) e[co] *= inv;
    }
    __syncthreads();   // col prefix complete before lookups

    // ---- phase C: Sauvola per pixel (f = e[] in registers) ----
    const int lr = t >> 4, lc = t & 15;
    const int gi = ti * TS + lr, gj = tj * TS + lc;
    const float xv = xs[(size_t)gi * W_ + gj];
    const float alpha = alphaP[0];

    const int wins[6] = {3, 5, 7, 11, 15, 19};
    float th1 = 0.f;
#pragma unroll
    for (int wi = 0; wi < 6; ++wi) {
        const int r = wins[wi] >> 1;
        const int r0 = max(gi - r, 0), r1i = min(gi + r, H_ - 1);
        const int c0 = max(gj - r, 0), c1 = min(gj + r, W_ - 1);
        const float invc = 1.f / (float)((r1i - r0 + 1) * (c1 - c0 + 1));
        const int top = lr + R9 - r, bot = lr + R9 + r + 1;
        const int lef = lc + R9 - r, rig = lc + R9 + r + 1;
        const float s1 = I1[bot * PSTR + rig] - I1[top * PSTR + rig]
                       - I1[bot * PSTR + lef] + I1[top * PSTR + lef];
        const float s2 = I2[bot * PSTR + rig] - I2[top * PSTR + rig]
                       - I2[bot * PSTR + lef] + I2[top * PSTR + lef];
        const float Ex = s1 * invc;
        const float Ex2 = s2 * invc;
        const float dev = sqrtf(fmaxf(Ex2 - Ex * Ex, 1e-6f));
        const float th = Ex * (1.f + kArr[wi] * (dev / RArr[wi] - 1.f));
        th1 = fmaf(e[wi], th, th1);
    }
    outp[(size_t)s * HW_ + (size_t)gi * W_ + gj] = (xv - th1) * alpha;
}

// ---------------------------------------------------------------------------
extern "C" void kernel_launch(void* const* d_in, const int* in_sizes, int n_in,
                              void* d_out, int out_size, void* d_ws, size_t ws_size,
                              hipStream_t stream) {
    const float* x   = (const float*)d_in[0];
    const float* w0  = (const float*)d_in[1];  const float* b0 = (const float*)d_in[2];
    const float* w1  = (const float*)d_in[3];  const float* b1 = (const float*)d_in[4];
    const float* w2  = (const float*)d_in[5];  const float* b2 = (const float*)d_in[6];
    const float* w3  = (const float*)d_in[7];  const float* b3 = (const float*)d_in[8];
    const float* w4  = (const float*)d_in[9];  const float* b4 = (const float*)d_in[10];
    const float* w5  = (const float*)d_in[11]; const float* b5 = (const float*)d_in[12];
    const float* wf  = (const float*)d_in[13]; const float* bf = (const float*)d_in[14];
    const float* kA  = (const float*)d_in[15];
    const float* RA  = (const float*)d_in[16];
    const float* alp = (const float*)d_in[17];
    float* out = (float*)d_out;
    (void)n_in; (void)in_sizes; (void)out_size;

    // partials + stats live in the TAIL of d_out: each iteration writes them
    // before reading; only the final chunk's conv2_sauvola overwrites the
    // tail, and that happens after the last partials/stats use.
    float* partials = out + (OUT_ELEMS - PMAX_FLOATS - 256);
    float* stats    = out + (OUT_ELEMS - 224);

    // ---- choose samples-per-launch from ws_size (deterministic) ----
    auto need = [](int nb) -> size_t {
        size_t o = 0;
        auto al = [&](size_t bytes) { o += (bytes + 255) & ~(size_t)255; };
        al((size_t)nb * HW_ * 20 * 2);          // bufA (bf16)
        al((size_t)nb * HW_ * 24 * 2);          // bufB (bf16)
        al(1664 * 2); al(1664 * 2); al(1664 * 2); al(2688 * 2);
        al(5376 * 2); al(7424 * 2); al(3712 * 2);
        return o;
    };
    int nb = 1;
    if (ws_size >= need(4)) nb = 4;
    else if (ws_size >= need(2)) nb = 2;

    char* ws = (char*)d_ws;
    size_t off = 0;
    auto alloc = [&](size_t bytes) -> void* {
        void* p = ws + off;
        off += (bytes + 255) & ~(size_t)255;
        return p;
    };
    bf16*  bufA = (bf16*)alloc((size_t)nb * HW_ * 20 * 2);
    bf16*  bufB = (bf16*)alloc((size_t)nb * HW_ * 24 * 2);
    bf16* r0 = (bf16*)alloc(1664 * 2);
    bf16* r1 = (bf16*)alloc(1664 * 2);
    bf16* r2 = (bf16*)alloc(1664 * 2);
    bf16* r3 = (bf16*)alloc(2688 * 2);
    bf16* r4 = (bf16*)alloc(5376 * 2);
    bf16* r5 = (bf16*)alloc(7424 * 2);
    bf16* rf = (bf16*)alloc(3712 * 2);

    const dim3 blk(BDIM);
    const int cg = nb * NBLK;

    repack_all<<<7, blk, 0, stream>>>(w0, w1, w2, w3, w4, w5, wf,
                                      r0, r1, r2, r3, r4, r5, rf);

    for (int it = 0; it < B_ / nb; ++it) {
        const float* xc   = x   + (size_t)it * nb * HW_;
        float*       outc = out + (size_t)it * nb * HW_;

        conv_mfma<1, 8, 4, 1, true><<<cg, blk, 0, stream>>>(xc, nullptr, r0, b0, bufA, partials);
        reduce_stats<4><<<nb * 4, blk, 0, stream>>>(partials, stats);

        conv_mfma<4, 8, 8, 2, false><<<cg, blk, 0, stream>>>(bufA, stats, r1, b1, bufB, partials);
        reduce_stats<8><<<nb * 8, blk, 0, stream>>>(partials, stats);

        conv_mfma<8, 8, 12, 2, false><<<cg, blk, 0, stream>>>(bufB, stats, r2, b2, bufA, partials);
        reduce_stats<12><<<nb * 12, blk, 0, stream>>>(partials, stats);

        conv_mfma<12, 16, 16, 2, false><<<cg, blk, 0, stream>>>(bufA, stats, r3, b3, bufB, partials);
        reduce_stats<16><<<nb * 16, blk, 0, stream>>>(partials, stats);

        conv_mfma<16, 16, 20, 2, false><<<cg, blk, 0, stream>>>(bufB, stats, r4, b4, bufA, partials);
        reduce_stats<20><<<nb * 20, blk, 0, stream>>>(partials, stats);

        conv_mfma<20, 24, 24, 2, false><<<cg, blk, 0, stream>>>(bufA, stats, r5, b5, bufB, partials);
        reduce_stats<24><<<nb * 24, blk, 0, stream>>>(partials, stats);

        conv2_sauvola<<<cg, blk, 0, stream>>>(
            bufB, stats, rf, bf, xc, kA, RA, alp, outc);
    }
}